// Round 1
// baseline (1428.576 us; speedup 1.0000x reference)
//
#include <hip/hip_runtime.h>
#include <cmath>

namespace {
constexpr int Bn = 2;
constexpr int Sn = 2048;
constexpr int Cn = 1024;
constexpr int Hn = 16;
constexpr int Dn = 64;
constexpr int Mrows = Bn * Sn;  // 4096
}

// Y = X[M,C] @ W[C,C]^T  (NT GEMM, 64x64 tile, 256 thr, 4x4 micro-tile)
// mode 0: dst[m*C + c] = y              (plain row-major, final proj)
// mode 1: reshape to [B,H,S,D] + RoPE   (q/k proj)
// mode 2: reshape to [B,H,S,D] only     (v proj)
__global__ __launch_bounds__(256) void proj_gemm(
    const float* __restrict__ X, const float* __restrict__ W,
    float* __restrict__ dst, int mode)
{
  __shared__ float As[64][20];
  __shared__ float Bs[64][20];
  const int tid = threadIdx.x;
  const int tx = tid & 15, ty = tid >> 4;
  const int mBase = blockIdx.y << 6, nBase = blockIdx.x << 6;
  const int lrow = tid >> 2, lk = (tid & 3) << 2;
  const float* Ap = X + (size_t)(mBase + lrow) * Cn + lk;
  const float* Bp = W + (size_t)(nBase + lrow) * Cn + lk;
  float acc[4][4] = {};
  for (int k0 = 0; k0 < Cn; k0 += 16) {
    const float4 av = *(const float4*)(Ap + k0);
    const float4 bv = *(const float4*)(Bp + k0);
    *(float4*)&As[lrow][lk] = av;
    *(float4*)&Bs[lrow][lk] = bv;
    __syncthreads();
#pragma unroll
    for (int kg = 0; kg < 4; ++kg) {
      float4 a[4], b[4];
#pragma unroll
      for (int i = 0; i < 4; ++i) a[i] = *(const float4*)&As[ty + 16 * i][kg << 2];
#pragma unroll
      for (int j = 0; j < 4; ++j) b[j] = *(const float4*)&Bs[tx + 16 * j][kg << 2];
#pragma unroll
      for (int i = 0; i < 4; ++i)
#pragma unroll
        for (int j = 0; j < 4; ++j)
          acc[i][j] += a[i].x * b[j].x + a[i].y * b[j].y +
                       a[i].z * b[j].z + a[i].w * b[j].w;
    }
    __syncthreads();
  }

  if (mode == 0) {
#pragma unroll
    for (int i = 0; i < 4; ++i) {
      const int m = mBase + ty + 16 * i;
#pragma unroll
      for (int j = 0; j < 4; ++j)
        dst[(size_t)m * Cn + nBase + tx + 16 * j] = acc[i][j];
    }
  } else {
    const int h = nBase >> 6;  // 64-wide tile = exactly one head
#pragma unroll
    for (int i = 0; i < 4; ++i) {
      const int m = mBase + ty + 16 * i;
      const int b = m >> 11, s = m & (Sn - 1);
      float* base = dst + (((size_t)(b * Hn + h)) * Sn + s) * Dn;
      if (mode == 2) {
#pragma unroll
        for (int j = 0; j < 4; ++j) base[tx + 16 * j] = acc[i][j];
      } else {
        // RoPE: out[d] = y[d]*cos - y[d+32]*sin ; out[d+32] = y[d+32]*cos + y[d]*sin
        // cols held by this thread: tx+16j -> pairs (j, j+2) are (d, d+32)
#pragma unroll
        for (int jj = 0; jj < 2; ++jj) {
          const int d1 = tx + 16 * jj;  // < 32
          const float invf = 1.0f / powf(10000.0f, (float)d1 * (1.0f / 32.0f));
          float sn, cs;
          sincosf((float)s * invf, &sn, &cs);
          const float y1 = acc[i][jj], y2 = acc[i][jj + 2];
          base[d1]      = y1 * cs - y2 * sn;
          base[d1 + 32] = y2 * cs + y1 * sn;
        }
      }
    }
  }
}

// scores[z, m, n] = 0.125 * sum_d qh[z,m,d] * kh[z,n,d]   (z = b*H+h)
__global__ __launch_bounds__(256) void scores_gemm(
    const float* __restrict__ qh, const float* __restrict__ kh,
    float* __restrict__ attn)
{
  __shared__ float As[64][20];
  __shared__ float Bs[64][20];
  const int tid = threadIdx.x;
  const int tx = tid & 15, ty = tid >> 4;
  const int z = blockIdx.z;
  const int mBase = blockIdx.y << 6, nBase = blockIdx.x << 6;
  const float* A = qh + (size_t)z * Sn * Dn;
  const float* Bm = kh + (size_t)z * Sn * Dn;
  const int lrow = tid >> 2, lk = (tid & 3) << 2;
  float acc[4][4] = {};
#pragma unroll
  for (int k0 = 0; k0 < Dn; k0 += 16) {
    *(float4*)&As[lrow][lk] = *(const float4*)(A + (size_t)(mBase + lrow) * Dn + k0 + lk);
    *(float4*)&Bs[lrow][lk] = *(const float4*)(Bm + (size_t)(nBase + lrow) * Dn + k0 + lk);
    __syncthreads();
#pragma unroll
    for (int kg = 0; kg < 4; ++kg) {
      float4 a[4], b[4];
#pragma unroll
      for (int i = 0; i < 4; ++i) a[i] = *(const float4*)&As[ty + 16 * i][kg << 2];
#pragma unroll
      for (int j = 0; j < 4; ++j) b[j] = *(const float4*)&Bs[tx + 16 * j][kg << 2];
#pragma unroll
      for (int i = 0; i < 4; ++i)
#pragma unroll
        for (int j = 0; j < 4; ++j)
          acc[i][j] += a[i].x * b[j].x + a[i].y * b[j].y +
                       a[i].z * b[j].z + a[i].w * b[j].w;
    }
    __syncthreads();
  }
  float* outp = attn + (size_t)z * Sn * Sn;
#pragma unroll
  for (int i = 0; i < 4; ++i) {
    const int m = mBase + ty + 16 * i;
#pragma unroll
    for (int j = 0; j < 4; ++j)
      outp[(size_t)m * Sn + nBase + tx + 16 * j] = acc[i][j] * 0.125f;
  }
}

// in-place row softmax over last dim (rows of 2048)
__global__ __launch_bounds__(256) void softmax_rows(float* __restrict__ attn)
{
  float* p = attn + (size_t)blockIdx.x * Sn;
  const int t = threadIdx.x;
  float4 x0 = ((const float4*)p)[t];
  float4 x1 = ((const float4*)p)[t + 256];
  float m = fmaxf(fmaxf(fmaxf(x0.x, x0.y), fmaxf(x0.z, x0.w)),
                  fmaxf(fmaxf(x1.x, x1.y), fmaxf(x1.z, x1.w)));
#pragma unroll
  for (int off = 32; off; off >>= 1) m = fmaxf(m, __shfl_xor(m, off));
  __shared__ float redm[4], reds[4];
  const int wv = t >> 6;
  if ((t & 63) == 0) redm[wv] = m;
  __syncthreads();
  m = fmaxf(fmaxf(redm[0], redm[1]), fmaxf(redm[2], redm[3]));
  x0.x = expf(x0.x - m); x0.y = expf(x0.y - m);
  x0.z = expf(x0.z - m); x0.w = expf(x0.w - m);
  x1.x = expf(x1.x - m); x1.y = expf(x1.y - m);
  x1.z = expf(x1.z - m); x1.w = expf(x1.w - m);
  float s = ((x0.x + x0.y) + (x0.z + x0.w)) + ((x1.x + x1.y) + (x1.z + x1.w));
#pragma unroll
  for (int off = 32; off; off >>= 1) s += __shfl_xor(s, off);
  if ((t & 63) == 0) reds[wv] = s;
  __syncthreads();
  s = (reds[0] + reds[1]) + (reds[2] + reds[3]);
  const float inv = 1.0f / s;
  x0.x *= inv; x0.y *= inv; x0.z *= inv; x0.w *= inv;
  x1.x *= inv; x1.y *= inv; x1.z *= inv; x1.w *= inv;
  ((float4*)p)[t] = x0;
  ((float4*)p)[t + 256] = x1;
}

// ctx[b, m, h*64 + d] = sum_j attn[z,m,j] * vh[z,j,d]   (NN GEMM, N=64)
__global__ __launch_bounds__(256) void pv_gemm(
    const float* __restrict__ attn, const float* __restrict__ vh,
    float* __restrict__ ctx)
{
  __shared__ float As[64][20];
  __shared__ float Vs[16][68];
  const int tid = threadIdx.x;
  const int tx = tid & 15, ty = tid >> 4;
  const int mBase = blockIdx.x << 6;
  const int z = blockIdx.y;
  const int b = z >> 4, h = z & 15;
  const float* A = attn + (size_t)z * Sn * Sn;
  const float* V = vh + (size_t)z * Sn * Dn;
  const int lrow = tid >> 2, lk = (tid & 3) << 2;   // A: 64 rows x 16 k
  const int vrow = tid >> 4, vcol = (tid & 15) << 2; // V: 16 k x 64 d
  float4 acc4[4] = {};
  for (int k0 = 0; k0 < Sn; k0 += 16) {
    *(float4*)&As[lrow][lk] = *(const float4*)(A + (size_t)(mBase + lrow) * Sn + k0 + lk);
    *(float4*)&Vs[vrow][vcol] = *(const float4*)(V + (size_t)(k0 + vrow) * Dn + vcol);
    __syncthreads();
#pragma unroll
    for (int kg = 0; kg < 4; ++kg) {
      float4 va[4];
#pragma unroll
      for (int t2 = 0; t2 < 4; ++t2)
        va[t2] = *(const float4*)&Vs[(kg << 2) + t2][tx << 2];
#pragma unroll
      for (int i = 0; i < 4; ++i) {
        const float4 a = *(const float4*)&As[ty + 16 * i][kg << 2];
        acc4[i] += va[0] * a.x + va[1] * a.y + va[2] * a.z + va[3] * a.w;
      }
    }
    __syncthreads();
  }
#pragma unroll
  for (int i = 0; i < 4; ++i) {
    const int m = mBase + ty + 16 * i;  // s index
    float* cp = ctx + ((size_t)b * Sn + m) * Cn + h * Dn + (tx << 2);
    *(float4*)cp = acc4[i];
  }
}

extern "C" void kernel_launch(void* const* d_in, const int* in_sizes, int n_in,
                              void* d_out, int out_size, void* d_ws, size_t ws_size,
                              hipStream_t stream)
{
  const float* q  = (const float*)d_in[0];
  const float* k  = (const float*)d_in[1];
  const float* v  = (const float*)d_in[2];
  const float* Wq = (const float*)d_in[3];
  const float* Wk = (const float*)d_in[4];
  const float* Wv = (const float*)d_in[5];
  const float* Wo = (const float*)d_in[6];

  float* out  = (float*)d_out;                       // [B,S,C]   4M floats
  float* attn = out + (size_t)Mrows * Cn;            // [B,H,S,S] 134M floats
  float* qh  = (float*)d_ws;                         // [B,H,S,D] 4M floats
  float* kh  = qh + (size_t)Mrows * Cn;              // 4M floats
  float* ctx = kh + (size_t)Mrows * Cn;              // [B,S,C]   4M floats
  float* vh  = out;  // stash vh in out-region; final proj overwrites it last

  dim3 gProj(Cn / 64, Mrows / 64);                   // (16, 64)
  proj_gemm<<<gProj, 256, 0, stream>>>(q, Wq, qh, 1);
  proj_gemm<<<gProj, 256, 0, stream>>>(k, Wk, kh, 1);
  proj_gemm<<<gProj, 256, 0, stream>>>(v, Wv, vh, 2);

  dim3 gS(Sn / 64, Sn / 64, Bn * Hn);                // (32, 32, 32)
  scores_gemm<<<gS, 256, 0, stream>>>(qh, kh, attn);

  softmax_rows<<<Bn * Hn * Sn, 256, 0, stream>>>(attn);

  dim3 gPV(Sn / 64, Bn * Hn);                        // (32, 32)
  pv_gemm<<<gPV, 256, 0, stream>>>(attn, vh, ctx);

  proj_gemm<<<gProj, 256, 0, stream>>>(ctx, Wo, out, 0);
}

// Round 2
// 826.084 us; speedup vs baseline: 1.7293x; 1.7293x over previous
//
#include <hip/hip_runtime.h>
#include <cmath>

typedef __bf16 bhalf;
typedef __bf16 bf16x4 __attribute__((ext_vector_type(4)));
typedef __bf16 bf16x8 __attribute__((ext_vector_type(8)));
typedef float f32x4 __attribute__((ext_vector_type(4)));

#define MFMA16(a, b, c) __builtin_amdgcn_mfma_f32_16x16x32_bf16(a, b, c, 0, 0, 0)

namespace {
constexpr int Bn = 2, Sn = 2048, Cn = 1024, Hn = 16, Dn = 64;
constexpr int Zn = Bn * Hn;     // 32
constexpr int Mn = Bn * Sn;     // 4096
}

__device__ __forceinline__ void cvt_hilo8(const float4& v0, const float4& v1,
                                          bf16x8& hi, bf16x8& lo) {
  float f[8] = {v0.x, v0.y, v0.z, v0.w, v1.x, v1.y, v1.z, v1.w};
#pragma unroll
  for (int i = 0; i < 8; ++i) {
    bhalf h = (bhalf)f[i];
    hi[i] = h;
    lo[i] = (bhalf)(f[i] - (float)h);
  }
}

// Y = A[M,C] @ W[C,C]^T via split-bf16 MFMA. Block: 256 thr / 4 waves,
// tile 64(M)x64(N); wave w owns rows [mB+16w, +16), all 64 cols (4 C-frags).
// MODE 0: out_f32[m*C+n] = y                       (final projection)
// MODE 1: RoPE + reshape, write hi/lo bf16 [z][s][64]   (q/k proj)
// MODE 2: reshape TRANSPOSED, write bf16 vt [z][d][S]   (v proj)
// A_BF16: A given as hi/lo bf16 pair (ctx) instead of fp32.
template <int MODE, bool A_BF16>
__global__ __launch_bounds__(256) void proj_mfma(
    const void* __restrict__ Av, const void* __restrict__ AvLo,
    const float* __restrict__ W, float* __restrict__ out_f32,
    bhalf* __restrict__ dst_hi, bhalf* __restrict__ dst_lo) {
  __shared__ bhalf BsH[64][40];  // [n-local][k-local], stride 80B (2-way banks)
  __shared__ bhalf BsL[64][40];
  const int tid = threadIdx.x;
  const int lane = tid & 63, w = tid >> 6;
  const int l15 = lane & 15, lg = lane >> 4;
  const int nB = blockIdx.x << 6, mB = blockIdx.y << 6;
  const int row = mB + w * 16 + l15;  // A row loaded by this lane
  f32x4 acc[4] = {};

  const int sr = tid >> 2, sc = (tid & 3) << 3;  // staging: row 0..63, k 0..24
  for (int k0 = 0; k0 < Cn; k0 += 32) {
    // stage W tile (64 cols x 32 k) -> hi/lo bf16 LDS
    {
      const float* wp = W + (size_t)(nB + sr) * Cn + k0 + sc;
      float4 w0 = *(const float4*)wp;
      float4 w1 = *(const float4*)(wp + 4);
      bf16x8 h, l;
      cvt_hilo8(w0, w1, h, l);
      *(bf16x8*)&BsH[sr][sc] = h;
      *(bf16x8*)&BsL[sr][sc] = l;
    }
    __syncthreads();
    bf16x8 aH, aL;
    if constexpr (A_BF16) {
      aH = *(const bf16x8*)((const bhalf*)Av + (size_t)row * Cn + k0 + lg * 8);
      aL = *(const bf16x8*)((const bhalf*)AvLo + (size_t)row * Cn + k0 + lg * 8);
    } else {
      const float* A = (const float*)Av;
      float4 a0 = *(const float4*)(A + (size_t)row * Cn + k0 + lg * 8);
      float4 a1 = *(const float4*)(A + (size_t)row * Cn + k0 + lg * 8 + 4);
      cvt_hilo8(a0, a1, aH, aL);
    }
#pragma unroll
    for (int j = 0; j < 4; ++j) {
      bf16x8 bH = *(const bf16x8*)&BsH[16 * j + l15][lg * 8];
      bf16x8 bL = *(const bf16x8*)&BsL[16 * j + l15][lg * 8];
      acc[j] = MFMA16(aH, bH, acc[j]);
      acc[j] = MFMA16(aH, bL, acc[j]);
      acc[j] = MFMA16(aL, bH, acc[j]);
    }
    __syncthreads();
  }

  const int mRow = mB + w * 16 + lg * 4;  // + r
  if constexpr (MODE == 0) {
#pragma unroll
    for (int j = 0; j < 4; ++j) {
      const int n = nB + 16 * j + l15;
#pragma unroll
      for (int r = 0; r < 4; ++r)
        out_f32[(size_t)(mRow + r) * Cn + n] = acc[j][r];
    }
  } else if constexpr (MODE == 1) {
    const int hh = nB >> 6;
#pragma unroll
    for (int jj = 0; jj < 2; ++jj) {
      const int d1 = 16 * jj + l15;  // < 32
      const float invf = 1.0f / powf(10000.0f, (float)d1 * (1.0f / 32.0f));
#pragma unroll
      for (int r = 0; r < 4; ++r) {
        const int m = mRow + r;
        const int b = m >> 11, s = m & (Sn - 1);
        float sn, cs;
        sincosf((float)s * invf, &sn, &cs);
        const float y1 = acc[jj][r], y2 = acc[jj + 2][r];
        const float o1 = y1 * cs - y2 * sn;
        const float o2 = y2 * cs + y1 * sn;
        const size_t base = (((size_t)(b * Hn + hh)) * Sn + s) * Dn;
        bhalf h1 = (bhalf)o1, h2 = (bhalf)o2;
        dst_hi[base + d1] = h1;
        dst_lo[base + d1] = (bhalf)(o1 - (float)h1);
        dst_hi[base + d1 + 32] = h2;
        dst_lo[base + d1 + 32] = (bhalf)(o2 - (float)h2);
      }
    }
  } else {  // MODE 2: vt[z][d][s] plain bf16
    const int hh = nB >> 6;
#pragma unroll
    for (int j = 0; j < 4; ++j) {
      const int d = 16 * j + l15;
#pragma unroll
      for (int r = 0; r < 4; ++r) {
        const int m = mRow + r;
        const int b = m >> 11, s = m & (Sn - 1);
        dst_hi[(((size_t)(b * Hn + hh)) * Dn + d) * Sn + s] = (bhalf)acc[j][r];
      }
    }
  }
}

// Fused scores -> softmax -> attn-write -> PV. One block = 16 q-rows of one
// (b,h); 4 waves each own a 512-key strip. Pass A: QK^T (split-bf16 MFMA)
// -> rowsum of exp. Pass B: recompute QK^T (bitwise identical), write
// normalized attn fp32 once, feed P(bf16) x V^T via MFMA into ctx.
__global__ __launch_bounds__(256) void attn_fused(
    const bhalf* __restrict__ qhH, const bhalf* __restrict__ qhL,
    const bhalf* __restrict__ khH, const bhalf* __restrict__ khL,
    const bhalf* __restrict__ vt, float* __restrict__ attn,
    bhalf* __restrict__ ctxH, bhalf* __restrict__ ctxL) {
  __shared__ bhalf ps[4][16][40];     // per-wave P chunk [q][key-local]
  __shared__ float obuf[4][16][68];   // [wave][q][d] partials
  __shared__ float lsum[4][16];
  __shared__ float linv[16];

  const int tid = threadIdx.x, lane = tid & 63, w = tid >> 6;
  const int l15 = lane & 15, lg = lane >> 4;
  // swizzle: XCD (gx&7) pinned to z&7 so each XCD's L2 keeps its K/V panels
  const int gx = blockIdx.x;
  const int z = (((gx >> 3) >> 7) << 3) | (gx & 7);
  const int qb = (gx >> 3) & 127;
  const int sB = qb << 4;

  // Q fragments (hi/lo, 2 K-slices of 32 d) — shared by all key tiles
  const size_t qBase = ((size_t)z * Sn + sB) * Dn + (size_t)l15 * Dn + lg * 8;
  bf16x8 qH[2], qL[2];
#pragma unroll
  for (int sl = 0; sl < 2; ++sl) {
    qH[sl] = *(const bf16x8*)(qhH + qBase + sl * 32);
    qL[sl] = *(const bf16x8*)(qhL + qBase + sl * 32);
  }
  const size_t kRow = (size_t)z * Sn * Dn;

  // ---- pass A: row sums of exp(score) ----
  float sum[4] = {0.f, 0.f, 0.f, 0.f};
  for (int t = 0; t < 32; ++t) {
    const int kb = (w << 9) + (t << 4);
    const bhalf* kp = khH + kRow + (size_t)(kb + l15) * Dn + lg * 8;
    const bhalf* kq = khL + kRow + (size_t)(kb + l15) * Dn + lg * 8;
    bf16x8 kH0 = *(const bf16x8*)kp, kH1 = *(const bf16x8*)(kp + 32);
    bf16x8 kL0 = *(const bf16x8*)kq, kL1 = *(const bf16x8*)(kq + 32);
    f32x4 c = {};
    c = MFMA16(qH[0], kH0, c); c = MFMA16(qH[1], kH1, c);
    c = MFMA16(qH[0], kL0, c); c = MFMA16(qH[1], kL1, c);
    c = MFMA16(qL[0], kH0, c); c = MFMA16(qL[1], kH1, c);
#pragma unroll
    for (int r = 0; r < 4; ++r) sum[r] += expf(c[r] * 0.125f);
  }
#pragma unroll
  for (int off = 1; off < 16; off <<= 1)
#pragma unroll
    for (int r = 0; r < 4; ++r) sum[r] += __shfl_xor(sum[r], off);
  if (l15 == 0) {
#pragma unroll
    for (int r = 0; r < 4; ++r) lsum[w][lg * 4 + r] = sum[r];
  }
  __syncthreads();
  if (tid < 16)
    linv[tid] = 1.0f / (lsum[0][tid] + lsum[1][tid] + lsum[2][tid] + lsum[3][tid]);
  __syncthreads();
  float invr[4];
#pragma unroll
  for (int r = 0; r < 4; ++r) invr[r] = linv[lg * 4 + r];

  // ---- pass B: recompute scores, write attn, PV ----
  f32x4 acc[4] = {};
  for (int cc = 0; cc < 16; ++cc) {
    const int kb = (w << 9) + (cc << 5);
#pragma unroll
    for (int tt = 0; tt < 2; ++tt) {
      const int kbt = kb + (tt << 4);
      const bhalf* kp = khH + kRow + (size_t)(kbt + l15) * Dn + lg * 8;
      const bhalf* kq = khL + kRow + (size_t)(kbt + l15) * Dn + lg * 8;
      bf16x8 kH0 = *(const bf16x8*)kp, kH1 = *(const bf16x8*)(kp + 32);
      bf16x8 kL0 = *(const bf16x8*)kq, kL1 = *(const bf16x8*)(kq + 32);
      f32x4 c = {};
      c = MFMA16(qH[0], kH0, c); c = MFMA16(qH[1], kH1, c);
      c = MFMA16(qH[0], kL0, c); c = MFMA16(qH[1], kL1, c);
      c = MFMA16(qL[0], kH0, c); c = MFMA16(qL[1], kH1, c);
#pragma unroll
      for (int r = 0; r < 4; ++r) {
        const float p = expf(c[r] * 0.125f) * invr[r];
        attn[((size_t)z * Sn + sB + lg * 4 + r) * Sn + kbt + l15] = p;
        ps[w][lg * 4 + r][(tt << 4) + l15] = (bhalf)p;
      }
    }
    // PV: C[d][q] += V^T(d x 32keys) * P^T(32keys x q)
    bf16x8 pb = *(const bf16x8*)&ps[w][l15][lg * 8];
#pragma unroll
    for (int g = 0; g < 4; ++g) {
      const bf16x8 va = *(const bf16x8*)(vt + ((size_t)z * Dn + g * 16 + l15) * Sn + kb + lg * 8);
      acc[g] = MFMA16(va, pb, acc[g]);
    }
  }

  // ---- cross-wave reduce + ctx(hi/lo) write ----
  __syncthreads();
#pragma unroll
  for (int g = 0; g < 4; ++g)
#pragma unroll
    for (int r = 0; r < 4; ++r)
      obuf[w][l15][g * 16 + lg * 4 + r] = acc[g][r];
  __syncthreads();
  {
    const int q = tid >> 4, d4 = (tid & 15) << 2;
    f32x4 rs = *(const f32x4*)&obuf[0][q][d4];
    rs += *(const f32x4*)&obuf[1][q][d4];
    rs += *(const f32x4*)&obuf[2][q][d4];
    rs += *(const f32x4*)&obuf[3][q][d4];
    const int b = z >> 4, hh = z & 15;
    const size_t off = ((size_t)b * Sn + sB + q) * Cn + hh * Dn + d4;
    bf16x4 hv, lv;
#pragma unroll
    for (int e = 0; e < 4; ++e) {
      bhalf h = (bhalf)rs[e];
      hv[e] = h;
      lv[e] = (bhalf)(rs[e] - (float)h);
    }
    *(bf16x4*)(ctxH + off) = hv;
    *(bf16x4*)(ctxL + off) = lv;
  }
}

extern "C" void kernel_launch(void* const* d_in, const int* in_sizes, int n_in,
                              void* d_out, int out_size, void* d_ws, size_t ws_size,
                              hipStream_t stream) {
  const float* q = (const float*)d_in[0];
  const float* k = (const float*)d_in[1];
  const float* v = (const float*)d_in[2];
  const float* Wq = (const float*)d_in[3];
  const float* Wk = (const float*)d_in[4];
  const float* Wv = (const float*)d_in[5];
  const float* Wo = (const float*)d_in[6];

  float* out = (float*)d_out;                       // [B,S,C] 4M f32
  float* attn = out + (size_t)Mn * Cn;              // [B,H,S,S] 134M f32
  bhalf* vt = (bhalf*)d_out;                        // stash V^T (8MB) in out region

  bhalf* qhH = (bhalf*)d_ws;                        // 6 x 8MB = 48MB ws
  bhalf* qhL = qhH + (size_t)Mn * Cn;
  bhalf* khH = qhL + (size_t)Mn * Cn;
  bhalf* khL = khH + (size_t)Mn * Cn;
  bhalf* ctxH = khL + (size_t)Mn * Cn;
  bhalf* ctxL = ctxH + (size_t)Mn * Cn;

  dim3 gP(Cn / 64, Mn / 64);  // (16, 64)
  proj_mfma<1, false><<<gP, 256, 0, stream>>>(q, nullptr, Wq, nullptr, qhH, qhL);
  proj_mfma<1, false><<<gP, 256, 0, stream>>>(k, nullptr, Wk, nullptr, khH, khL);
  proj_mfma<2, false><<<gP, 256, 0, stream>>>(v, nullptr, Wv, nullptr, vt, nullptr);

  attn_fused<<<Zn * (Sn / 16), 256, 0, stream>>>(qhH, qhL, khH, khL, vt, attn, ctxH, ctxL);

  proj_mfma<0, true><<<gP, 256, 0, stream>>>(ctxH, ctxL, Wo, out, nullptr, nullptr);
}

// Round 3
// 519.039 us; speedup vs baseline: 2.7523x; 1.5916x over previous
//
#include <hip/hip_runtime.h>
#include <cmath>

typedef __bf16 bhalf;
typedef __bf16 bf16x4 __attribute__((ext_vector_type(4)));
typedef __bf16 bf16x8 __attribute__((ext_vector_type(8)));
typedef float f32x4 __attribute__((ext_vector_type(4)));

#define MFMA16(a, b, c) __builtin_amdgcn_mfma_f32_16x16x32_bf16(a, b, c, 0, 0, 0)

namespace {
constexpr int Bn = 2, Sn = 2048, Cn = 1024, Hn = 16, Dn = 64;
constexpr int Zn = Bn * Hn;     // 32
constexpr int Mn = Bn * Sn;     // 4096
}

__device__ __forceinline__ void cvt_hilo8(const float4& v0, const float4& v1,
                                          bf16x8& hi, bf16x8& lo) {
  float f[8] = {v0.x, v0.y, v0.z, v0.w, v1.x, v1.y, v1.z, v1.w};
#pragma unroll
  for (int i = 0; i < 8; ++i) {
    bhalf h = (bhalf)f[i];
    hi[i] = h;
    lo[i] = (bhalf)(f[i] - (float)h);
  }
}

// Y = A[M,C] @ W[C,C]^T via split-bf16 MFMA. (unchanged from round 2)
template <int MODE, bool A_BF16>
__global__ __launch_bounds__(256) void proj_mfma(
    const void* __restrict__ Av, const void* __restrict__ AvLo,
    const float* __restrict__ W, float* __restrict__ out_f32,
    bhalf* __restrict__ dst_hi, bhalf* __restrict__ dst_lo) {
  __shared__ bhalf BsH[64][40];
  __shared__ bhalf BsL[64][40];
  const int tid = threadIdx.x;
  const int lane = tid & 63, w = tid >> 6;
  const int l15 = lane & 15, lg = lane >> 4;
  const int nB = blockIdx.x << 6, mB = blockIdx.y << 6;
  const int row = mB + w * 16 + l15;
  f32x4 acc[4] = {};

  const int sr = tid >> 2, sc = (tid & 3) << 3;
  for (int k0 = 0; k0 < Cn; k0 += 32) {
    {
      const float* wp = W + (size_t)(nB + sr) * Cn + k0 + sc;
      float4 w0 = *(const float4*)wp;
      float4 w1 = *(const float4*)(wp + 4);
      bf16x8 h, l;
      cvt_hilo8(w0, w1, h, l);
      *(bf16x8*)&BsH[sr][sc] = h;
      *(bf16x8*)&BsL[sr][sc] = l;
    }
    __syncthreads();
    bf16x8 aH, aL;
    if constexpr (A_BF16) {
      aH = *(const bf16x8*)((const bhalf*)Av + (size_t)row * Cn + k0 + lg * 8);
      aL = *(const bf16x8*)((const bhalf*)AvLo + (size_t)row * Cn + k0 + lg * 8);
    } else {
      const float* A = (const float*)Av;
      float4 a0 = *(const float4*)(A + (size_t)row * Cn + k0 + lg * 8);
      float4 a1 = *(const float4*)(A + (size_t)row * Cn + k0 + lg * 8 + 4);
      cvt_hilo8(a0, a1, aH, aL);
    }
#pragma unroll
    for (int j = 0; j < 4; ++j) {
      bf16x8 bH = *(const bf16x8*)&BsH[16 * j + l15][lg * 8];
      bf16x8 bL = *(const bf16x8*)&BsL[16 * j + l15][lg * 8];
      acc[j] = MFMA16(aH, bH, acc[j]);
      acc[j] = MFMA16(aH, bL, acc[j]);
      acc[j] = MFMA16(aL, bH, acc[j]);
    }
    __syncthreads();
  }

  const int mRow = mB + w * 16 + lg * 4;
  if constexpr (MODE == 0) {
#pragma unroll
    for (int j = 0; j < 4; ++j) {
      const int n = nB + 16 * j + l15;
#pragma unroll
      for (int r = 0; r < 4; ++r)
        out_f32[(size_t)(mRow + r) * Cn + n] = acc[j][r];
    }
  } else if constexpr (MODE == 1) {
    const int hh = nB >> 6;
#pragma unroll
    for (int jj = 0; jj < 2; ++jj) {
      const int d1 = 16 * jj + l15;
      const float invf = 1.0f / powf(10000.0f, (float)d1 * (1.0f / 32.0f));
#pragma unroll
      for (int r = 0; r < 4; ++r) {
        const int m = mRow + r;
        const int b = m >> 11, s = m & (Sn - 1);
        float sn, cs;
        sincosf((float)s * invf, &sn, &cs);
        const float y1 = acc[jj][r], y2 = acc[jj + 2][r];
        const float o1 = y1 * cs - y2 * sn;
        const float o2 = y2 * cs + y1 * sn;
        const size_t base = (((size_t)(b * Hn + hh)) * Sn + s) * Dn;
        bhalf h1 = (bhalf)o1, h2 = (bhalf)o2;
        dst_hi[base + d1] = h1;
        dst_lo[base + d1] = (bhalf)(o1 - (float)h1);
        dst_hi[base + d1 + 32] = h2;
        dst_lo[base + d1 + 32] = (bhalf)(o2 - (float)h2);
      }
    }
  } else {
    const int hh = nB >> 6;
#pragma unroll
    for (int j = 0; j < 4; ++j) {
      const int d = 16 * j + l15;
#pragma unroll
      for (int r = 0; r < 4; ++r) {
        const int m = mRow + r;
        const int b = m >> 11, s = m & (Sn - 1);
        dst_hi[(((size_t)(b * Hn + hh)) * Dn + d) * Sn + s] = (bhalf)acc[j][r];
      }
    }
  }
}

// Fused attention. Block = 32 q-rows of one z; 4 waves split keys (512 each).
// Pass A: scores -> e=exp (unnormalized) -> PV MFMA on e (bf16) + rowsums.
// Pass B: recompute scores -> p = e*inv -> coalesced nontemporal fp32 stores.
// Epilogue: cross-wave ctx reduce, scale by inv, hi/lo bf16 write.
__global__ __launch_bounds__(256) void attn_fused(
    const bhalf* __restrict__ qhH, const bhalf* __restrict__ qhL,
    const bhalf* __restrict__ khH, const bhalf* __restrict__ khL,
    const bhalf* __restrict__ vt, float* __restrict__ attn,
    bhalf* __restrict__ ctxH, bhalf* __restrict__ ctxL) {
  __shared__ union PB {
    float pt[32][68];   // pass B p-tile / epilogue obuf (rows 0..15)
    bhalf ps[32][72];   // pass A e-tile (transpose buffer)
  } pb_[4];
  __shared__ float lsum[4][32];
  __shared__ float linv[32];

  const int tid = threadIdx.x, lane = tid & 63, w = tid >> 6;
  const int l15 = lane & 15, lg = lane >> 4;
  const int gx = blockIdx.x;
  const int z = ((gx >> 3) >> 6) * 8 + (gx & 7);   // z&7 pinned to XCD slot
  const int qb = (gx >> 3) & 63;
  const int sB = qb * 32;
  const int bb = z >> 4, hh = z & 15;

  const size_t kRow = (size_t)z * Sn * Dn;
  // Q fragments for both 16-row q-frags, both 32-d k-slices
  bf16x8 qH[2][2], qL[2][2];
#pragma unroll
  for (int qf = 0; qf < 2; ++qf)
#pragma unroll
    for (int sl = 0; sl < 2; ++sl) {
      const size_t qoff = ((size_t)z * Sn + sB + qf * 16 + l15) * Dn + sl * 32 + lg * 8;
      qH[qf][sl] = *(const bf16x8*)(qhH + qoff);
      qL[qf][sl] = *(const bf16x8*)(qhL + qoff);
    }

  const int kw = w << 9;  // wave's key base
  float sum[2][4] = {};
  f32x4 acc[2][4] = {};

  // ---------------- pass A ----------------
  for (int cc = 0; cc < 8; ++cc) {
    const int kb0 = kw + cc * 64;
#pragma unroll
    for (int t = 0; t < 4; ++t) {
      const int kb = kb0 + t * 16;
      const bhalf* kp = khH + kRow + (size_t)(kb + l15) * Dn + lg * 8;
      const bhalf* kq = khL + kRow + (size_t)(kb + l15) * Dn + lg * 8;
      bf16x8 kH0 = *(const bf16x8*)kp, kH1 = *(const bf16x8*)(kp + 32);
      bf16x8 kL0 = *(const bf16x8*)kq, kL1 = *(const bf16x8*)(kq + 32);
#pragma unroll
      for (int qf = 0; qf < 2; ++qf) {
        f32x4 cA = {}, cB = {};
        cA = MFMA16(qH[qf][0], kH0, cA); cA = MFMA16(qH[qf][1], kH1, cA);
        cB = MFMA16(qH[qf][0], kL0, cB); cB = MFMA16(qH[qf][1], kL1, cB);
        cA = MFMA16(qL[qf][0], kH0, cA); cA = MFMA16(qL[qf][1], kH1, cA);
        f32x4 c = cA + cB;
#pragma unroll
        for (int r = 0; r < 4; ++r) {
          const float e = __expf(c[r] * 0.125f);
          sum[qf][r] += e;
          pb_[w].ps[qf * 16 + lg * 4 + r][t * 16 + l15] = (bhalf)e;
        }
      }
    }
    // PV on unnormalized e
#pragma unroll
    for (int ks = 0; ks < 2; ++ks) {
      bf16x8 pb0 = *(const bf16x8*)&pb_[w].ps[l15][ks * 32 + lg * 8];
      bf16x8 pb1 = *(const bf16x8*)&pb_[w].ps[16 + l15][ks * 32 + lg * 8];
#pragma unroll
      for (int g = 0; g < 4; ++g) {
        const bf16x8 va = *(const bf16x8*)(vt + ((size_t)z * Dn + g * 16 + l15) * Sn + kb0 + ks * 32 + lg * 8);
        acc[0][g] = MFMA16(va, pb0, acc[0][g]);
        acc[1][g] = MFMA16(va, pb1, acc[1][g]);
      }
    }
  }

  // ---------------- rowsum reduce ----------------
#pragma unroll
  for (int off = 1; off < 16; off <<= 1)
#pragma unroll
    for (int qf = 0; qf < 2; ++qf)
#pragma unroll
      for (int r = 0; r < 4; ++r) sum[qf][r] += __shfl_xor(sum[qf][r], off);
  if (l15 == 0) {
#pragma unroll
    for (int qf = 0; qf < 2; ++qf)
#pragma unroll
      for (int r = 0; r < 4; ++r) lsum[w][qf * 16 + lg * 4 + r] = sum[qf][r];
  }
  __syncthreads();
  if (tid < 32)
    linv[tid] = 1.0f / (lsum[0][tid] + lsum[1][tid] + lsum[2][tid] + lsum[3][tid]);
  __syncthreads();
  float invr[2][4];
#pragma unroll
  for (int qf = 0; qf < 2; ++qf)
#pragma unroll
    for (int r = 0; r < 4; ++r) invr[qf][r] = linv[qf * 16 + lg * 4 + r];

  // ---------------- pass B: attn write ----------------
  for (int cc = 0; cc < 8; ++cc) {
    const int kb0 = kw + cc * 64;
#pragma unroll
    for (int t = 0; t < 4; ++t) {
      const int kb = kb0 + t * 16;
      const bhalf* kp = khH + kRow + (size_t)(kb + l15) * Dn + lg * 8;
      const bhalf* kq = khL + kRow + (size_t)(kb + l15) * Dn + lg * 8;
      bf16x8 kH0 = *(const bf16x8*)kp, kH1 = *(const bf16x8*)(kp + 32);
      bf16x8 kL0 = *(const bf16x8*)kq, kL1 = *(const bf16x8*)(kq + 32);
#pragma unroll
      for (int qf = 0; qf < 2; ++qf) {
        f32x4 cA = {}, cB = {};
        cA = MFMA16(qH[qf][0], kH0, cA); cA = MFMA16(qH[qf][1], kH1, cA);
        cB = MFMA16(qH[qf][0], kL0, cB); cB = MFMA16(qH[qf][1], kL1, cB);
        cA = MFMA16(qL[qf][0], kH0, cA); cA = MFMA16(qL[qf][1], kH1, cA);
        f32x4 c = cA + cB;
#pragma unroll
        for (int r = 0; r < 4; ++r)
          pb_[w].pt[qf * 16 + lg * 4 + r][t * 16 + l15] =
              __expf(c[r] * 0.125f) * invr[qf][r];
      }
    }
#pragma unroll
    for (int qf = 0; qf < 2; ++qf)
#pragma unroll
      for (int i = 0; i < 4; ++i) {
        const int row = i * 4 + lg;
        f32x4 vv = *(const f32x4*)&pb_[w].pt[qf * 16 + row][l15 * 4];
        float* ap = attn + ((size_t)z * Sn + sB + qf * 16 + row) * Sn + kb0 + l15 * 4;
        __builtin_nontemporal_store(vv, (f32x4*)ap);
      }
  }

  // ---------------- epilogue: ctx reduce ----------------
  __syncthreads();
#pragma unroll
  for (int qf = 0; qf < 2; ++qf) {
#pragma unroll
    for (int g = 0; g < 4; ++g)
#pragma unroll
      for (int r = 0; r < 4; ++r)
        pb_[w].pt[l15][g * 16 + lg * 4 + r] = acc[qf][g][r];
    __syncthreads();
    {
      const int q = tid >> 4, d4 = (tid & 15) << 2;
      f32x4 rs = *(const f32x4*)&pb_[0].pt[q][d4];
      rs += *(const f32x4*)&pb_[1].pt[q][d4];
      rs += *(const f32x4*)&pb_[2].pt[q][d4];
      rs += *(const f32x4*)&pb_[3].pt[q][d4];
      const float sc = linv[qf * 16 + q];
      rs *= sc;
      const size_t off = ((size_t)bb * Sn + sB + qf * 16 + q) * Cn + hh * Dn + d4;
      bf16x4 hv, lv;
#pragma unroll
      for (int e = 0; e < 4; ++e) {
        bhalf h = (bhalf)rs[e];
        hv[e] = h;
        lv[e] = (bhalf)(rs[e] - (float)h);
      }
      *(bf16x4*)(ctxH + off) = hv;
      *(bf16x4*)(ctxL + off) = lv;
    }
    __syncthreads();
  }
}

extern "C" void kernel_launch(void* const* d_in, const int* in_sizes, int n_in,
                              void* d_out, int out_size, void* d_ws, size_t ws_size,
                              hipStream_t stream) {
  const float* q = (const float*)d_in[0];
  const float* k = (const float*)d_in[1];
  const float* v = (const float*)d_in[2];
  const float* Wq = (const float*)d_in[3];
  const float* Wk = (const float*)d_in[4];
  const float* Wv = (const float*)d_in[5];
  const float* Wo = (const float*)d_in[6];

  float* out = (float*)d_out;                       // [B,S,C] 4M f32
  float* attn = out + (size_t)Mn * Cn;              // [B,H,S,S] 134M f32
  bhalf* vt = (bhalf*)d_out;                        // stash V^T (8MB) in out region

  bhalf* qhH = (bhalf*)d_ws;                        // 6 x 8MB = 48MB ws
  bhalf* qhL = qhH + (size_t)Mn * Cn;
  bhalf* khH = qhL + (size_t)Mn * Cn;
  bhalf* khL = khH + (size_t)Mn * Cn;
  bhalf* ctxH = khL + (size_t)Mn * Cn;
  bhalf* ctxL = ctxH + (size_t)Mn * Cn;

  dim3 gP(Cn / 64, Mn / 64);  // (16, 64)
  proj_mfma<1, false><<<gP, 256, 0, stream>>>(q, nullptr, Wq, nullptr, qhH, qhL);
  proj_mfma<1, false><<<gP, 256, 0, stream>>>(k, nullptr, Wk, nullptr, khH, khL);
  proj_mfma<2, false><<<gP, 256, 0, stream>>>(v, nullptr, Wv, nullptr, vt, nullptr);

  attn_fused<<<Zn * (Sn / 32), 256, 0, stream>>>(qhH, qhL, khH, khL, vt, attn, ctxH, ctxL);

  proj_mfma<0, true><<<gP, 256, 0, stream>>>(ctxH, ctxL, Wo, out, nullptr, nullptr);
}